// Round 9
// baseline (343.573 us; speedup 1.0000x reference)
//
#include <hip/hip_runtime.h>

// PointNet on MI355X. B=32, P=2048, K=16, NHID=128, NCLS=10.
//   K1 knn      : brute-force d2; per-lane streaming top-3 VALUES (med3 chain + value-only m4),
//                 indices s1/s2 tracked, s3 recovered by conditional bit-match rescan; SET-based
//                 emission via ballot binary-search for V; exact fallback on __any(k4<V) (~0.4%).
//   K2 layer1   : msg = relu(pos_j*(A+B) + (b1a - pos_p*B)); v = msg @ W1b (MFMA); h1 = relu(max_k v + b1b).
//                 FUSED mid_gemm: h1 rows go to LDS tile h1t[64][168] (not global); after the main
//                 loop, W2a^T is staged into the dead Wbt/mt space (k<128: 256B swizzled rows
//                 identical to W1b; k-hi: [128][80B] strip) and each wave runs the 8x5-MFMA
//                 u2' epilogue + bias, writing u2p directly. Same t-order & bf16 casts as the old
//                 mid_gemm => u2p bit-identical. Saves h1e 20MB W + 20MB R + one dispatch.
//   K3 layer2   : msg = relu(u2'[j] - pos_p*R); v = msg @ W2b (MFMA); fused global max pool.
//                 LDS-resident W2b^T (r8) + RESTORED r7-style 1-deep u2p payload prefetch
//                 (r8 removed it: layer2 regressed ~9us; the 64B/lane gather needs the pipeline).
//   K4 cls      : out = g @ Wc + bc
// MFMA layouts per verified m89/m97 mappings.

typedef __bf16 bf16x8 __attribute__((ext_vector_type(8)));
typedef float  f32x4  __attribute__((ext_vector_type(4)));

#define LDSA __attribute__((aligned(16)))
#define WAVE_LDS_SYNC() __asm__ volatile("s_waitcnt lgkmcnt(0)" ::: "memory")

// ---------------------------------------------------------------- K1: KNN
__global__ __launch_bounds__(512, 4) void knn_kernel(const float* __restrict__ pos,
                                                     int* __restrict__ nbr) {
  __shared__ LDSA float4 P4[2048];  // {x,y,z,|p|^2}
  const int blk = blockIdx.x;
  const int b = blk >> 5;
  const int tid = threadIdx.x;
  const size_t bbase = (size_t)b * 2048;
  for (int idx = tid; idx < 2048; idx += 512) {
    const float* pp = pos + (bbase + idx) * 3;
    float x = pp[0], y = pp[1], z = pp[2];
    P4[idx] = make_float4(x, y, z, fmaf(z, z, fmaf(y, y, x * x)));
  }
  __syncthreads();
  const int wave = tid >> 6, lane = tid & 63;
  const int p0 = (blk & 31) * 64 + wave * 8;   // 8 points per wave
  const unsigned long long below = (1ull << lane) - 1ull;
  const float FINF = __uint_as_float(0x7F800000u);
  for (int it = 0; it < 8; ++it) {
    const int pl = p0 + it;
    const float4 P = P4[pl];
    // ---- phase 1: streaming per-lane sorted top-3 values (+m4); indices s1,s2 only ----
    float m1 = FINF, m2 = FINF, m3 = FINF, m4 = FINF;
    unsigned s1 = 0, s2 = 0;
#pragma unroll 8
    for (int i = 0; i < 32; ++i) {
      int c = lane + (i << 6);
      float4 Q = P4[c];
      float d2 = (P.w + Q.w) - 2.0f * fmaf(P.z, Q.z, fmaf(P.y, Q.y, P.x * Q.x));
      bool c1 = d2 < m1, c2 = d2 < m2;
      float nm4 = __builtin_amdgcn_fmed3f(m3, m4, d2);
      float nm3 = __builtin_amdgcn_fmed3f(m2, m3, d2);
      float nm2 = __builtin_amdgcn_fmed3f(m1, m2, d2);
      float nm1 = fminf(m1, d2);
      s2 = c1 ? s1 : (c2 ? (unsigned)c : s2);
      s1 = c1 ? (unsigned)c : s1;
      m1 = nm1; m2 = nm2; m3 = nm3; m4 = nm4;
    }
    // ---- monotone float->u32 keys ----
    unsigned k1 = __float_as_uint(m1); k1 = ((int)k1 < 0) ? ~k1 : (k1 | 0x80000000u);
    unsigned k2 = __float_as_uint(m2); k2 = ((int)k2 < 0) ? ~k2 : (k2 | 0x80000000u);
    unsigned k3 = __float_as_uint(m3); k3 = ((int)k3 < 0) ? ~k3 : (k3 | 0x80000000u);
    unsigned k4 = __float_as_uint(m4); k4 = ((int)k4 < 0) ? ~k4 : (k4 | 0x80000000u);
    // ---- phase 2: binary search for V = 16th smallest buffered key ----
    unsigned v = 0;
#pragma unroll
    for (int bit = 31; bit >= 0; --bit) {
      unsigned t = v | (1u << bit);
      int cnt = __popcll(__ballot(k1 < t)) + __popcll(__ballot(k2 < t)) +
                __popcll(__ballot(k3 < t));
      if (cnt < 16) v = t;  // keep invariant count(< v) < 16; final v = 16th smallest
    }
    const unsigned V = v;
    // ---- s3 recovery rescan: only when some lane's 3rd key can be emitted ----
    unsigned s3 = 0;
    if (__any(k3 <= V)) {
      const unsigned m3b = __float_as_uint(m3);
#pragma unroll 8
      for (int i = 0; i < 32; ++i) {
        int c = lane + (i << 6);
        float4 Q = P4[c];
        float d2 = (P.w + Q.w) - 2.0f * fmaf(P.z, Q.z, fmaf(P.y, Q.y, P.x * Q.x));
        if (__float_as_uint(d2) == m3b) s3 = (unsigned)c;
      }
    }
    const long long outbase = ((long long)bbase + pl) * 16;
    if (__any(k4 < V)) {
      // ---- exact fallback (~0.4%): 16-round u64 pop-with-refill ----
      unsigned long long K1 = ((unsigned long long)k1 << 32) | s1;
      unsigned long long K2 = ((unsigned long long)k2 << 32) | s2;
      unsigned long long K3 = ((unsigned long long)k3 << 32) | s3;
      unsigned long long lastk = 0;
      for (int r = 0; r < 16; ++r) {
        unsigned long long k = K1, kmin = K1;
#pragma unroll
        for (int off = 1; off < 64; off <<= 1) {
          unsigned long long o = __shfl_xor(kmin, off);
          kmin = (o < kmin) ? o : kmin;
        }
        if (lane == r) nbr[outbase + r] = (int)(kmin & 0xFFFFFFFFull);
        if (k == kmin) { lastk = k; K1 = K2; K2 = K3; K3 = ~0ull; }
        if (r < 15 && __any(K1 == ~0ull)) {
          if (K1 == ~0ull) {
            unsigned long long best = ~0ull;
            for (int i = 0; i < 32; ++i) {
              int c = lane + (i << 6);
              float4 Q = P4[c];
              float d2 = (P.w + Q.w) - 2.0f * fmaf(P.z, Q.z, fmaf(P.y, Q.y, P.x * Q.x));
              unsigned u = __float_as_uint(d2);
              u = ((int)u < 0) ? ~u : (u | 0x80000000u);
              unsigned long long kc = ((unsigned long long)u << 32) | (unsigned)c;
              bool ok = (kc > lastk) & (kc < best);
              best = ok ? kc : best;
            }
            K1 = best;
          }
        }
      }
    } else {
      // ---- set emission: all keys < V, plus (16 - count) of the == V ties ----
      unsigned long long L1 = __ballot(k1 < V), L2 = __ballot(k2 < V), L3 = __ballot(k3 < V);
      unsigned long long E1 = __ballot(k1 == V), E2 = __ballot(k2 == V), E3 = __ballot(k3 == V);
      int cA = __popcll(L1), cB = cA + __popcll(L2), cT = cB + __popcll(L3);
      int eA = __popcll(E1), eB = eA + __popcll(E2);
      {
        bool lt = k1 < V, eq = k1 == V;
        int plt = __popcll(L1 & below);
        int peq = cT + __popcll(E1 & below);
        int p = lt ? plt : peq;
        if (lt || (eq && peq < 16)) nbr[outbase + p] = (int)s1;
      }
      {
        bool lt = k2 < V, eq = k2 == V;
        int plt = cA + __popcll(L2 & below);
        int peq = cT + eA + __popcll(E2 & below);
        int p = lt ? plt : peq;
        if (lt || (eq && peq < 16)) nbr[outbase + p] = (int)s2;
      }
      {
        bool lt = k3 < V, eq = k3 == V;
        int plt = cB + __popcll(L3 & below);
        int peq = cT + eB + __popcll(E3 & below);
        int p = lt ? plt : peq;
        if (lt || (eq && peq < 16)) nbr[outbase + p] = (int)s3;
      }
    }
  }
}

// ---------------------------------------------------------------- K2: layer 1 + fused u2' gemm
__global__ __launch_bounds__(256, 2) void layer1_kernel(
    const float* __restrict__ pos, const int* __restrict__ nbr,
    const float* __restrict__ W1a, const float* __restrict__ b1a,
    const float* __restrict__ W1b, const float* __restrict__ b1b,
    const float* __restrict__ W2a, const float* __restrict__ b2a,
    __bf16* __restrict__ u2p) {
  // LDS map: [0,32768)      Wbt: W1b^T 128x256B swizzled (main loop); then W2a^T k<128 (epilogue)
  //          [32768,50176)  mt: 4 waves x [16][136] bf16 (main); then Whi: W2a^T k-hi [128][80B]
  //          [50176,52736)  base: 4 waves x 160 f32 (8 blocks x stride 20)
  //          [52736,74240)  h1t: block tile [64][168] bf16 = [h1 | pos | 0]
  __shared__ LDSA char smem[74240];
  __bf16* Wbt = (__bf16*)smem;
  const int tid = threadIdx.x;
  for (int idx = tid; idx < 16384; idx += 256) {
    int k = idx >> 7, n = idx & 127;
    int byteoff = n * 256 + ((k * 2) ^ ((n & 7) << 4));
    *(__bf16*)((char*)Wbt + byteoff) = (__bf16)W1b[idx];
  }
  __syncthreads();
  const int wave = tid >> 6, lane = tid & 63;
  const int q = lane >> 4, c15 = lane & 15;
  __bf16* mt = (__bf16*)(smem + 32768) + wave * 2176;   // [16][136]
  float* base = (float*)(smem + 50176) + wave * 160;    // 8 blocks x stride 20
  __bf16* h1t = (__bf16*)(smem + 52736);                // [64][168]
  const int cb = lane & 7, k0 = lane >> 3, C0 = cb * 16;
  float4 s0h[4], s1h[4], s2h[4];  // (A+B) rows for this lane's 16 channels
#pragma unroll
  for (int i = 0; i < 4; ++i) {
    float4 a0 = *(const float4*)&W1a[      C0 + 4 * i], r0 = *(const float4*)&W1a[384 + C0 + 4 * i];
    float4 a1 = *(const float4*)&W1a[128 + C0 + 4 * i], r1 = *(const float4*)&W1a[512 + C0 + 4 * i];
    float4 a2 = *(const float4*)&W1a[256 + C0 + 4 * i], r2 = *(const float4*)&W1a[640 + C0 + 4 * i];
    s0h[i] = make_float4(a0.x + r0.x, a0.y + r0.y, a0.z + r0.z, a0.w + r0.w);
    s1h[i] = make_float4(a1.x + r1.x, a1.y + r1.y, a1.z + r1.z, a1.w + r1.w);
    s2h[i] = make_float4(a2.x + r2.x, a2.y + r2.y, a2.z + r2.z, a2.w + r2.w);
  }
  const int c2 = lane * 2;
  const int bslot = (lane >> 3) * 20 + (lane & 7) * 2;  // channel c2 at (c2>>4)*20+(c2&15)
  const float br0a = W1a[384 + c2], br0b = W1a[384 + c2 + 1];
  const float br1a = W1a[512 + c2], br1b = W1a[512 + c2 + 1];
  const float br2a = W1a[640 + c2], br2b = W1a[640 + c2 + 1];
  const float ba0 = b1a[c2], ba1 = b1a[c2 + 1];
  const float bbi0 = b1b[q * 32 + c15], bbi1 = b1b[q * 32 + 16 + c15];
  const int blk = blockIdx.x, b = blk >> 5;
  const size_t bbase = (size_t)b * 2048;
  const int p0 = (blk & 31) * 64 + wave * 16;
  const size_t row0 = bbase + p0;   // wave's first global row (for u2p epilogue)
  size_t node = row0;
  // prefetch it=0 indices + own pos
  int j0 = nbr[node * 16 + k0];
  int j1 = nbr[node * 16 + k0 + 8];
  float px = pos[node * 3], py = pos[node * 3 + 1], pz = pos[node * 3 + 2];
  for (int it = 0; it < 16; ++it) {
    const int j0c = j0, j1c = j1;
    const float xp = px, yp = py, zp = pz;
    const size_t nodec = node;
    const int rl = wave * 16 + it;  // local h1t row
    if (it < 15) {  // prefetch next iteration's indices + own pos
      node = nodec + 1;
      j0 = nbr[node * 16 + k0];
      j1 = nbr[node * 16 + k0 + 8];
      px = pos[node * 3]; py = pos[node * 3 + 1]; pz = pos[node * 3 + 2];
    }
    const float* pj0 = pos + (bbase + j0c) * 3;
    const float* pj1 = pos + (bbase + j1c) * 3;
    const float xa = pj0[0], ya = pj0[1], za = pj0[2];
    const float xb = pj1[0], yb = pj1[1], zb = pj1[2];
    float v0 = ba0 - fmaf(xp, br0a, fmaf(yp, br1a, zp * br2a));
    float v1 = ba1 - fmaf(xp, br0b, fmaf(yp, br1b, zp * br2b));
    *(float2*)&base[bslot] = make_float2(v0, v1);
    WAVE_LDS_SYNC();
    float4 bb[4];
#pragma unroll
    for (int i = 0; i < 4; ++i) bb[i] = *(const float4*)&base[cb * 20 + 4 * i];
#pragma unroll
    for (int r = 0; r < 2; ++r) {
      const float xj = r ? xb : xa, yj = r ? yb : ya, zj = r ? zb : za;
      bf16x8 o0, o1;
#pragma unroll
      for (int i = 0; i < 4; ++i) {
        float mx = fmaf(xj, s0h[i].x, fmaf(yj, s1h[i].x, fmaf(zj, s2h[i].x, bb[i].x)));
        float my = fmaf(xj, s0h[i].y, fmaf(yj, s1h[i].y, fmaf(zj, s2h[i].y, bb[i].y)));
        float mz = fmaf(xj, s0h[i].z, fmaf(yj, s1h[i].z, fmaf(zj, s2h[i].z, bb[i].z)));
        float mw = fmaf(xj, s0h[i].w, fmaf(yj, s1h[i].w, fmaf(zj, s2h[i].w, bb[i].w)));
        __bf16 e0 = (__bf16)fmaxf(mx, 0.f), e1 = (__bf16)fmaxf(my, 0.f);
        __bf16 e2 = (__bf16)fmaxf(mz, 0.f), e3 = (__bf16)fmaxf(mw, 0.f);
        if (i < 2) { o0[i * 4 + 0] = e0; o0[i * 4 + 1] = e1; o0[i * 4 + 2] = e2; o0[i * 4 + 3] = e3; }
        else { o1[(i - 2) * 4 + 0] = e0; o1[(i - 2) * 4 + 1] = e1; o1[(i - 2) * 4 + 2] = e2; o1[(i - 2) * 4 + 3] = e3; }
      }
      __bf16* dst = &mt[(k0 + 8 * r) * 136 + C0];
      *(bf16x8*)dst = o0;
      *(bf16x8*)(dst + 8) = o1;
    }
    WAVE_LDS_SYNC();
    bf16x8 af[4];
#pragma unroll
    for (int t = 0; t < 4; ++t)
      af[t] = *(const bf16x8*)&mt[c15 * 136 + t * 32 + q * 8];
    f32x4 acc[8] = {};
#pragma unroll
    for (int nt = 0; nt < 8; ++nt)
#pragma unroll
      for (int t = 0; t < 4; ++t) {
        const int row = nt * 16 + c15;
        bf16x8 bf = *(const bf16x8*)((const char*)Wbt +
                     row * 256 + (((t * 32 + q * 8) * 2) ^ ((row & 7) << 4)));
        acc[nt] = __builtin_amdgcn_mfma_f32_16x16x32_bf16(af[t], bf, acc[nt], 0, 0, 0);
      }
#pragma unroll
    for (int nt = 0; nt < 8; ++nt) {
      float m4 = fmaxf(fmaxf(acc[nt][0], acc[nt][1]), fmaxf(acc[nt][2], acc[nt][3]));
      m4 = fmaxf(m4, __shfl_xor(m4, 16));
      m4 = fmaxf(m4, __shfl_xor(m4, 32));
      if ((nt >> 1) == q) {
        float bias = (nt & 1) ? bbi1 : bbi0;
        h1t[rl * 168 + nt * 16 + c15] = (__bf16)fmaxf(m4 + bias, 0.f);  // h1 row -> LDS tile
      }
    }
    if (lane < 32) {  // append pos (bf16) + zero pad: cols 128..159
      __bf16 v = (__bf16)0.f;
      if (lane == 0) v = (__bf16)xp;
      else if (lane == 1) v = (__bf16)yp;
      else if (lane == 2) v = (__bf16)zp;
      h1t[rl * 168 + 128 + lane] = v;
    }
  }
  // ================= fused u2' = [h1|pos|0] @ W2a + b2a epilogue =================
  __syncthreads();  // B1: all waves done with Wbt/mt; h1t complete
  // pass 1: Wbt <- W2a^T (k<128, swizzled 256B rows); zero Whi strip [128][80B]
  for (int idx = tid; idx < 4096; idx += 256) {
    int k = idx >> 5, c4 = (idx & 31) * 4;
    float4 w = *(const float4*)&W2a[k * 128 + c4];
    *(__bf16*)((char*)smem + (c4 + 0) * 256 + ((k * 2) ^ (((c4 + 0) & 7) << 4))) = (__bf16)w.x;
    *(__bf16*)((char*)smem + (c4 + 1) * 256 + ((k * 2) ^ (((c4 + 1) & 7) << 4))) = (__bf16)w.y;
    *(__bf16*)((char*)smem + (c4 + 2) * 256 + ((k * 2) ^ (((c4 + 2) & 7) << 4))) = (__bf16)w.z;
    *(__bf16*)((char*)smem + (c4 + 3) * 256 + ((k * 2) ^ (((c4 + 3) & 7) << 4))) = (__bf16)w.w;
  }
  char* Whi = (char*)smem + 32768;  // [128 n][80 B] (k=128..159; >130 zero)
  for (int idx = tid; idx < 2560; idx += 256) ((unsigned*)Whi)[idx] = 0u;
  __syncthreads();  // B2: zero-fill done before k-hi writes
  for (int idx = tid; idx < 384; idx += 256) {
    int kk = idx >> 7, n = idx & 127;  // kk = 0..2 -> k = 128+kk
    *(__bf16*)(Whi + n * 80 + kk * 2) = (__bf16)W2a[(128 + kk) * 128 + n];
  }
  __syncthreads();  // B3: staging complete
  float biasr[8];
#pragma unroll
  for (int nt = 0; nt < 8; ++nt) biasr[nt] = b2a[nt * 16 + c15];
  bf16x8 af2[5];
#pragma unroll
  for (int t = 0; t < 5; ++t)
    af2[t] = *(const bf16x8*)&h1t[(wave * 16 + c15) * 168 + t * 32 + q * 8];
  f32x4 acc2[8] = {};
#pragma unroll
  for (int nt = 0; nt < 8; ++nt) {
    const int row = nt * 16 + c15;
#pragma unroll
    for (int t = 0; t < 4; ++t) {
      bf16x8 bf = *(const bf16x8*)((const char*)smem +
                   row * 256 + (((t * 32 + q * 8) * 2) ^ ((row & 7) << 4)));
      acc2[nt] = __builtin_amdgcn_mfma_f32_16x16x32_bf16(af2[t], bf, acc2[nt], 0, 0, 0);
    }
    bf16x8 bf4 = *(const bf16x8*)(Whi + row * 80 + q * 16);
    acc2[nt] = __builtin_amdgcn_mfma_f32_16x16x32_bf16(af2[4], bf4, acc2[nt], 0, 0, 0);
  }
#pragma unroll
  for (int nt = 0; nt < 8; ++nt) {
#pragma unroll
    for (int r = 0; r < 4; ++r)
      u2p[(row0 + q * 4 + r) * 128 + nt * 16 + c15] = (__bf16)(acc2[nt][r] + biasr[nt]);
  }
}

// ---------------------------------------------------------------- K3: layer 2 + fused max pool
__global__ __launch_bounds__(256, 2) void layer2_kernel(
    const float* __restrict__ pos, const int* __restrict__ nbr,
    const __bf16* __restrict__ u2p, const float* __restrict__ W2a,
    const float* __restrict__ W2b, const float* __restrict__ b2b,
    int* __restrict__ gG) {
  __shared__ LDSA char smem[52736];  // { Wbt 32KB live ; mt 17KB ; proj 2.5KB }
  __shared__ int gpart[128];
  __bf16* Wbt = (__bf16*)smem;
  const int tid = threadIdx.x;
  for (int idx = tid; idx < 16384; idx += 256) {
    int k = idx >> 7, n = idx & 127;
    int byteoff = n * 256 + ((k * 2) ^ ((n & 7) << 4));
    *(__bf16*)((char*)Wbt + byteoff) = (__bf16)W2b[idx];
  }
  if (tid < 128) gpart[tid] = 0;
  __syncthreads();
  const int wave = tid >> 6, lane = tid & 63;
  const int q = lane >> 4, c15 = lane & 15;
  __bf16* mt = (__bf16*)(smem + 32768) + wave * 2176;   // [16][136]
  float* proj = (float*)(smem + 50176) + wave * 160;    // 8 blocks x stride 20
  const int cb = lane & 7, k0 = lane >> 3, C0 = cb * 16;
  const int c2 = lane * 2;
  const int bslot = (lane >> 3) * 20 + (lane & 7) * 2;
  const float r0a = W2a[16384 + c2], r0b = W2a[16384 + c2 + 1];
  const float r1a = W2a[16512 + c2], r1b = W2a[16512 + c2 + 1];
  const float r2a = W2a[16640 + c2], r2b = W2a[16640 + c2 + 1];
  const float bbi0 = b2b[q * 32 + c15], bbi1 = b2b[q * 32 + 16 + c15];
  // XCD swizzle: graph g's 32 blocks -> one XCD (blk%8 assumed XCD round-robin; perf-only)
  const int lb = blockIdx.x;
  const int xcd = lb & 7, slot = lb >> 3;
  const int b = xcd + 8 * (slot >> 5);
  const int bi = slot & 31;
  const size_t bbase = (size_t)b * 2048;
  const int p0 = bi * 64 + wave * 16;
  size_t node = bbase + p0;
  int j0 = nbr[node * 16 + k0];
  int j1 = nbr[node * 16 + k0 + 8];
  float px = pos[node * 3], py = pos[node * 3 + 1], pz = pos[node * 3 + 2];
  // payload for it=0 (r7-style 1-deep pipeline)
  const __bf16* u0p = u2p + (size_t)(bbase + j0) * 128 + C0;
  const __bf16* u1p = u2p + (size_t)(bbase + j1) * 128 + C0;
  bf16x8 ua0 = *(const bf16x8*)u0p, ua1 = *(const bf16x8*)(u0p + 8);
  bf16x8 ub0 = *(const bf16x8*)u1p, ub1 = *(const bf16x8*)(u1p + 8);
  for (int it = 0; it < 16; ++it) {
    const float xp = px, yp = py, zp = pz;
    const size_t nodec = node;
    if (it < 15) {
      node = nodec + 1;
      j0 = nbr[node * 16 + k0];
      j1 = nbr[node * 16 + k0 + 8];
      px = pos[node * 3]; py = pos[node * 3 + 1]; pz = pos[node * 3 + 2];
    }
    float v0 = fmaf(xp, r0a, fmaf(yp, r1a, zp * r2a));
    float v1 = fmaf(xp, r0b, fmaf(yp, r1b, zp * r2b));
    *(float2*)&proj[bslot] = make_float2(v0, v1);
    WAVE_LDS_SYNC();
    float pj[16];
#pragma unroll
    for (int i = 0; i < 4; ++i) *(float4*)&pj[4 * i] = *(const float4*)&proj[cb * 20 + 4 * i];
#pragma unroll
    for (int r = 0; r < 2; ++r) {
      bf16x8 u0 = r ? ub0 : ua0, u1 = r ? ub1 : ua1;
      bf16x8 o0, o1;
#pragma unroll
      for (int e = 0; e < 8; ++e) o0[e] = (__bf16)fmaxf((float)u0[e] - pj[e], 0.f);
#pragma unroll
      for (int e = 0; e < 8; ++e) o1[e] = (__bf16)fmaxf((float)u1[e] - pj[8 + e], 0.f);
      __bf16* dst = &mt[(k0 + 8 * r) * 136 + C0];
      *(bf16x8*)dst = o0;
      *(bf16x8*)(dst + 8) = o1;
    }
    if (it < 15) {  // payload for it+1 into the SAME regs: flies across MFMA+epilogue
      const __bf16* g0 = u2p + (size_t)(bbase + j0) * 128 + C0;
      const __bf16* g1 = u2p + (size_t)(bbase + j1) * 128 + C0;
      ua0 = *(const bf16x8*)g0; ua1 = *(const bf16x8*)(g0 + 8);
      ub0 = *(const bf16x8*)g1; ub1 = *(const bf16x8*)(g1 + 8);
    }
    WAVE_LDS_SYNC();  // lgkmcnt only: vmcnt payload loads stay in flight
    bf16x8 af[4];
#pragma unroll
    for (int t = 0; t < 4; ++t)
      af[t] = *(const bf16x8*)&mt[c15 * 136 + t * 32 + q * 8];
    f32x4 acc[8] = {};
#pragma unroll
    for (int nt = 0; nt < 8; ++nt)
#pragma unroll
      for (int t = 0; t < 4; ++t) {
        const int row = nt * 16 + c15;
        bf16x8 bf = *(const bf16x8*)((const char*)Wbt +
                     row * 256 + (((t * 32 + q * 8) * 2) ^ ((row & 7) << 4)));
        acc[nt] = __builtin_amdgcn_mfma_f32_16x16x32_bf16(af[t], bf, acc[nt], 0, 0, 0);
      }
#pragma unroll
    for (int nt = 0; nt < 8; ++nt) {
      float m4 = fmaxf(fmaxf(acc[nt][0], acc[nt][1]), fmaxf(acc[nt][2], acc[nt][3]));
      m4 = fmaxf(m4, __shfl_xor(m4, 16));
      m4 = fmaxf(m4, __shfl_xor(m4, 32));
      if ((nt >> 1) == q) {
        float bias = (nt & 1) ? bbi1 : bbi0;
        float h = fmaxf(m4 + bias, 0.f);
        atomicMax(&gpart[nt * 16 + c15], __float_as_int(h));  // h>=0: int-max == float-max
      }
    }
  }
  __syncthreads();
  if (tid < 128) atomicMax(&gG[b * 128 + tid], gpart[tid]);
}

// ---------------------------------------------------------------- K4: classifier
__global__ __launch_bounds__(64) void cls_kernel(const int* __restrict__ gG,
                                                 const float* __restrict__ Wc,
                                                 const float* __restrict__ bc,
                                                 float* __restrict__ out) {
  const int b = blockIdx.x, lane = threadIdx.x;
  float g1 = __int_as_float(gG[b * 128 + lane]);
  float g2 = __int_as_float(gG[b * 128 + 64 + lane]);
  float accn[10];
#pragma unroll
  for (int n = 0; n < 10; ++n)
    accn[n] = g1 * Wc[lane * 10 + n] + g2 * Wc[(64 + lane) * 10 + n];
#pragma unroll
  for (int n = 0; n < 10; ++n) {
#pragma unroll
    for (int off = 32; off >= 1; off >>= 1) accn[n] += __shfl_xor(accn[n], off);
  }
  if (lane == 0) {
#pragma unroll
    for (int n = 0; n < 10; ++n) out[b * 10 + n] = accn[n] + bc[n];
  }
}

// ---------------------------------------------------------------- launcher
extern "C" void kernel_launch(void* const* d_in, const int* in_sizes, int n_in,
                              void* d_out, int out_size, void* d_ws, size_t ws_size,
                              hipStream_t stream) {
  const float* pos = (const float*)d_in[0];
  // d_in[1] = batch (unused: graphs are equal-size, sorted)
  const float* W1a = (const float*)d_in[2];
  const float* b1a = (const float*)d_in[3];
  const float* W1b = (const float*)d_in[4];
  const float* b1b = (const float*)d_in[5];
  const float* W2a = (const float*)d_in[6];
  const float* b2a = (const float*)d_in[7];
  const float* W2b = (const float*)d_in[8];
  const float* b2b = (const float*)d_in[9];
  const float* Wc  = (const float*)d_in[10];
  const float* bc  = (const float*)d_in[11];

  char* ws = (char*)d_ws;
  int*    nbr = (int*)ws;                          //  4 MB : [65536][16]
  // ws + 4 MB .. 24 MB: free (h1e eliminated by the layer1/mid_gemm fusion)
  __bf16* u2p = (__bf16*)(ws + 25165824);          // 16 MB : [65536][128] bf16
  int*    gG  = (int*)(ws + 41943040);             // 16 KB : [32][128]
  float*  out = (float*)d_out;

  hipMemsetAsync(gG, 0, 32 * 128 * sizeof(int), stream);  // relu>=0, bits(0)==0.0f
  knn_kernel<<<1024, 512, 0, stream>>>(pos, nbr);
  layer1_kernel<<<1024, 256, 0, stream>>>(pos, nbr, W1a, b1a, W1b, b1b, W2a, b2a, u2p);
  layer2_kernel<<<1024, 256, 0, stream>>>(pos, nbr, u2p, W2a, W2b, b2b, gG);
  cls_kernel<<<32, 64, 0, stream>>>(gG, Wc, bc, out);
}

// Round 10
// 330.584 us; speedup vs baseline: 1.0393x; 1.0393x over previous
//
#include <hip/hip_runtime.h>

// PointNet on MI355X. B=32, P=2048, K=16, NHID=128, NCLS=10.
//   K1 knn      : brute-force d2; per-lane streaming top-3+indices PLUS value-only m4
//                 (4th smallest, 1 extra med3/cand). SET-based selection: 32-step ballot binary
//                 search for V = 16th-smallest buffered key (over k1..k3), ballot-ranked scatter
//                 of {key<V} + (16-cnt) of {key==V}. Fallback trigger REFINED: exact pop-with-
//                 refill only when __any(k4 < V) (~0.4% of points vs 11% with k3) — a lane with
//                 k3<V<=k4 has all its <V keys buffered+indexed, so set emission is exact.
//                 d2 formula identical in all paths.
//   K2 layer1   : msg = relu(pos_j*(A+B) + (b1a - pos_p*B)); v = msg @ W1b (MFMA); h1 = relu(max_k v + b1b)
//                 Wave-private LDS (no block barriers in loop); nbr/pos prefetched one iter ahead.
//   K3 midgemm  : u2' = [h1|pos|0] @ W2a(all 131 rows) + b2a -> bf16. 4 row-tiles/block.
//   K4 layer2   : msg = relu(u2'[j] - pos_p*R); v = msg @ W2b (MFMA); fused global max pool.
//                 u2p gather bf16 + XCD swizzle for L2 residency.
//   K5 cls      : out = g @ Wc + bc
// MFMA layouts per verified m89/m97 mappings.
// NOTE (session ledger): this is the empirical optimum (332.089 us, round 4 bench). Layer-kernel
// restructures (dbuf single-drain r6; mid_gemm fusion r9) and polish (stride-20 r7, LDS-Wbt r8)
// all measured null/negative — layers are latency-structure-bound at ~2 blocks/CU; knn is at
// ~86% VALUBusy (near issue floor).

typedef __bf16 bf16x8 __attribute__((ext_vector_type(8)));
typedef float  f32x4  __attribute__((ext_vector_type(4)));

#define LDSA __attribute__((aligned(16)))
#define WAVE_LDS_SYNC() __asm__ volatile("s_waitcnt lgkmcnt(0)" ::: "memory")

// ---------------------------------------------------------------- K1: KNN
__global__ __launch_bounds__(512, 4) void knn_kernel(const float* __restrict__ pos,
                                                     int* __restrict__ nbr) {
  __shared__ LDSA float4 P4[2048];  // {x,y,z,|p|^2}
  const int blk = blockIdx.x;
  const int b = blk >> 5;
  const int tid = threadIdx.x;
  const size_t bbase = (size_t)b * 2048;
  for (int idx = tid; idx < 2048; idx += 512) {
    const float* pp = pos + (bbase + idx) * 3;
    float x = pp[0], y = pp[1], z = pp[2];
    P4[idx] = make_float4(x, y, z, fmaf(z, z, fmaf(y, y, x * x)));
  }
  __syncthreads();
  const int wave = tid >> 6, lane = tid & 63;
  const int p0 = (blk & 31) * 64 + wave * 8;   // 8 points per wave
  const unsigned long long below = (1ull << lane) - 1ull;
  const float FINF = __uint_as_float(0x7F800000u);
  for (int it = 0; it < 8; ++it) {
    const int pl = p0 + it;
    const float4 P = P4[pl];
    // ---- phase 1: streaming per-lane sorted top-3 (+ value-only 4th) ----
    float m1 = FINF, m2 = FINF, m3 = FINF, m4 = FINF;
    unsigned s1 = 0, s2 = 0, s3 = 0;
#pragma unroll 8
    for (int i = 0; i < 32; ++i) {
      int c = lane + (i << 6);
      float4 Q = P4[c];
      float d2 = (P.w + Q.w) - 2.0f * fmaf(P.z, Q.z, fmaf(P.y, Q.y, P.x * Q.x));
      bool c1 = d2 < m1, c2 = d2 < m2, c3 = d2 < m3;
      // values: med3 sorted-insert; m4 needs no compare (pure value tracking)
      float nm4 = __builtin_amdgcn_fmed3f(m3, m4, d2);
      float nm3 = __builtin_amdgcn_fmed3f(m2, m3, d2);
      float nm2 = __builtin_amdgcn_fmed3f(m1, m2, d2);
      float nm1 = fminf(m1, d2);
      s3 = c2 ? s2 : (c3 ? (unsigned)c : s3);
      s2 = c1 ? s1 : (c2 ? (unsigned)c : s2);
      s1 = c1 ? (unsigned)c : s1;
      m1 = nm1; m2 = nm2; m3 = nm3; m4 = nm4;
    }
    // ---- monotone float->u32 keys ----
    unsigned k1 = __float_as_uint(m1); k1 = ((int)k1 < 0) ? ~k1 : (k1 | 0x80000000u);
    unsigned k2 = __float_as_uint(m2); k2 = ((int)k2 < 0) ? ~k2 : (k2 | 0x80000000u);
    unsigned k3 = __float_as_uint(m3); k3 = ((int)k3 < 0) ? ~k3 : (k3 | 0x80000000u);
    unsigned k4 = __float_as_uint(m4); k4 = ((int)k4 < 0) ? ~k4 : (k4 | 0x80000000u);
    // ---- phase 2: binary search for V = 16th smallest buffered key ----
    unsigned v = 0;
#pragma unroll
    for (int bit = 31; bit >= 0; --bit) {
      unsigned t = v | (1u << bit);
      int cnt = __popcll(__ballot(k1 < t)) + __popcll(__ballot(k2 < t)) +
                __popcll(__ballot(k3 < t));
      if (cnt < 16) v = t;  // keep invariant count(< v) < 16; final v = 16th smallest
    }
    const unsigned V = v;
    const long long outbase = ((long long)bbase + pl) * 16;
    if (__any(k4 < V)) {
      // ---- exact fallback (~0.4%): a lane's UNBUFFERED 4th is < V => set emission
      //      would miss it. 16-round u64 pop-with-refill (exact, unchanged). ----
      unsigned long long K1 = ((unsigned long long)k1 << 32) | s1;
      unsigned long long K2 = ((unsigned long long)k2 << 32) | s2;
      unsigned long long K3 = ((unsigned long long)k3 << 32) | s3;
      unsigned long long lastk = 0;
      for (int r = 0; r < 16; ++r) {
        unsigned long long k = K1, kmin = K1;
#pragma unroll
        for (int off = 1; off < 64; off <<= 1) {
          unsigned long long o = __shfl_xor(kmin, off);
          kmin = (o < kmin) ? o : kmin;
        }
        if (lane == r) nbr[outbase + r] = (int)(kmin & 0xFFFFFFFFull);
        if (k == kmin) { lastk = k; K1 = K2; K2 = K3; K3 = ~0ull; }
        if (r < 15 && __any(K1 == ~0ull)) {
          if (K1 == ~0ull) {
            unsigned long long best = ~0ull;
            for (int i = 0; i < 32; ++i) {
              int c = lane + (i << 6);
              float4 Q = P4[c];
              float d2 = (P.w + Q.w) - 2.0f * fmaf(P.z, Q.z, fmaf(P.y, Q.y, P.x * Q.x));
              unsigned u = __float_as_uint(d2);
              u = ((int)u < 0) ? ~u : (u | 0x80000000u);
              unsigned long long kc = ((unsigned long long)u << 32) | (unsigned)c;
              bool ok = (kc > lastk) & (kc < best);
              best = ok ? kc : best;
            }
            K1 = best;
          }
        }
      }
    } else {
      // ---- set emission: all keys < V, plus (16 - count) of the == V ties ----
      unsigned long long L1 = __ballot(k1 < V), L2 = __ballot(k2 < V), L3 = __ballot(k3 < V);
      unsigned long long E1 = __ballot(k1 == V), E2 = __ballot(k2 == V), E3 = __ballot(k3 == V);
      int cA = __popcll(L1), cB = cA + __popcll(L2), cT = cB + __popcll(L3);
      int eA = __popcll(E1), eB = eA + __popcll(E2);
      {
        bool lt = k1 < V, eq = k1 == V;
        int plt = __popcll(L1 & below);
        int peq = cT + __popcll(E1 & below);
        int p = lt ? plt : peq;
        if (lt || (eq && peq < 16)) nbr[outbase + p] = (int)s1;
      }
      {
        bool lt = k2 < V, eq = k2 == V;
        int plt = cA + __popcll(L2 & below);
        int peq = cT + eA + __popcll(E2 & below);
        int p = lt ? plt : peq;
        if (lt || (eq && peq < 16)) nbr[outbase + p] = (int)s2;
      }
      {
        bool lt = k3 < V, eq = k3 == V;
        int plt = cB + __popcll(L3 & below);
        int peq = cT + eB + __popcll(E3 & below);
        int p = lt ? plt : peq;
        if (lt || (eq && peq < 16)) nbr[outbase + p] = (int)s3;
      }
    }
  }
}

// ---------------------------------------------------------------- K2: layer 1
__global__ __launch_bounds__(256, 2) void layer1_kernel(
    const float* __restrict__ pos, const int* __restrict__ nbr,
    const float* __restrict__ W1a, const float* __restrict__ b1a,
    const float* __restrict__ W1b, const float* __restrict__ b1b,
    __bf16* __restrict__ h1e) {
  __shared__ LDSA char smem[34816];  // Wbt aliased with { mt ; base }
  __bf16* Wbt = (__bf16*)smem;
  const int tid = threadIdx.x;
  // XOR-swizzled staging: row n stride 272 B (68 dw == 4 mod 32; x8 wraps -> same-(n>>3)
  // lanes 8-way conflict). byte ^= ((n>>3)&7)<<4 permutes 16B blocks, spreading banks.
  for (int idx = tid; idx < 16384; idx += 256) {
    int k = idx >> 7, n = idx & 127;
    int byteoff = n * 272 + ((k * 2) ^ (((n >> 3) & 7) << 4));
    *(__bf16*)((char*)Wbt + byteoff) = (__bf16)W1b[idx];
  }
  __syncthreads();
  const int wave = tid >> 6, lane = tid & 63;
  const int q = lane >> 4, c15 = lane & 15;
  bf16x8 bfr[8][4];  // W1b^T fragments resident (128 VGPRs)
#pragma unroll
  for (int nt = 0; nt < 8; ++nt)
#pragma unroll
    for (int t = 0; t < 4; ++t) {
      int row = nt * 16 + c15;
      int rbyte = row * 272 + (((t * 32 + q * 8) * 2) ^ (((row >> 3) & 7) << 4));
      bfr[nt][t] = *(const bf16x8*)((const char*)Wbt + rbyte);
    }
  __syncthreads();  // Wbt dead: space reused for mt/base
  __bf16* mt = (__bf16*)smem + wave * 2176;          // [16 rows][136]
  float* base = (float*)(smem + 17408) + wave * 128;
  const int cb = lane & 7, k0 = lane >> 3, C0 = cb * 16;
  float4 s0h[4], s1h[4], s2h[4];  // (A+B) rows for this lane's 16 channels
#pragma unroll
  for (int i = 0; i < 4; ++i) {
    float4 a0 = *(const float4*)&W1a[      C0 + 4 * i], r0 = *(const float4*)&W1a[384 + C0 + 4 * i];
    float4 a1 = *(const float4*)&W1a[128 + C0 + 4 * i], r1 = *(const float4*)&W1a[512 + C0 + 4 * i];
    float4 a2 = *(const float4*)&W1a[256 + C0 + 4 * i], r2 = *(const float4*)&W1a[640 + C0 + 4 * i];
    s0h[i] = make_float4(a0.x + r0.x, a0.y + r0.y, a0.z + r0.z, a0.w + r0.w);
    s1h[i] = make_float4(a1.x + r1.x, a1.y + r1.y, a1.z + r1.z, a1.w + r1.w);
    s2h[i] = make_float4(a2.x + r2.x, a2.y + r2.y, a2.z + r2.z, a2.w + r2.w);
  }
  const int c2 = lane * 2;
  const float br0a = W1a[384 + c2], br0b = W1a[384 + c2 + 1];
  const float br1a = W1a[512 + c2], br1b = W1a[512 + c2 + 1];
  const float br2a = W1a[640 + c2], br2b = W1a[640 + c2 + 1];
  const float ba0 = b1a[c2], ba1 = b1a[c2 + 1];
  const float bbi0 = b1b[q * 32 + c15], bbi1 = b1b[q * 32 + 16 + c15];
  const int blk = blockIdx.x, b = blk >> 5;
  const size_t bbase = (size_t)b * 2048;
  const int p0 = (blk & 31) * 64 + wave * 16;
  size_t node = bbase + p0;
  // prefetch it=0
  int j0 = nbr[node * 16 + k0];
  int j1 = nbr[node * 16 + k0 + 8];
  float px = pos[node * 3], py = pos[node * 3 + 1], pz = pos[node * 3 + 2];
  for (int it = 0; it < 16; ++it) {
    const int j0c = j0, j1c = j1;
    const float xp = px, yp = py, zp = pz;
    const size_t nodec = node;
    if (it < 15) {  // prefetch next iteration's indices + own pos
      node = nodec + 1;
      j0 = nbr[node * 16 + k0];
      j1 = nbr[node * 16 + k0 + 8];
      px = pos[node * 3]; py = pos[node * 3 + 1]; pz = pos[node * 3 + 2];
    }
    const float* pj0 = pos + (bbase + j0c) * 3;
    const float* pj1 = pos + (bbase + j1c) * 3;
    const float xa = pj0[0], ya = pj0[1], za = pj0[2];
    const float xb = pj1[0], yb = pj1[1], zb = pj1[2];
    float v0 = ba0 - fmaf(xp, br0a, fmaf(yp, br1a, zp * br2a));
    float v1 = ba1 - fmaf(xp, br0b, fmaf(yp, br1b, zp * br2b));
    *(float2*)&base[c2] = make_float2(v0, v1);
    WAVE_LDS_SYNC();
    float4 bb[4];
#pragma unroll
    for (int i = 0; i < 4; ++i) bb[i] = *(const float4*)&base[C0 + 4 * i];
#pragma unroll
    for (int r = 0; r < 2; ++r) {
      const float xj = r ? xb : xa, yj = r ? yb : ya, zj = r ? zb : za;
      bf16x8 o0, o1;
#pragma unroll
      for (int i = 0; i < 4; ++i) {
        float mx = fmaf(xj, s0h[i].x, fmaf(yj, s1h[i].x, fmaf(zj, s2h[i].x, bb[i].x)));
        float my = fmaf(xj, s0h[i].y, fmaf(yj, s1h[i].y, fmaf(zj, s2h[i].y, bb[i].y)));
        float mz = fmaf(xj, s0h[i].z, fmaf(yj, s1h[i].z, fmaf(zj, s2h[i].z, bb[i].z)));
        float mw = fmaf(xj, s0h[i].w, fmaf(yj, s1h[i].w, fmaf(zj, s2h[i].w, bb[i].w)));
        __bf16 e0 = (__bf16)fmaxf(mx, 0.f), e1 = (__bf16)fmaxf(my, 0.f);
        __bf16 e2 = (__bf16)fmaxf(mz, 0.f), e3 = (__bf16)fmaxf(mw, 0.f);
        if (i < 2) { o0[i * 4 + 0] = e0; o0[i * 4 + 1] = e1; o0[i * 4 + 2] = e2; o0[i * 4 + 3] = e3; }
        else { o1[(i - 2) * 4 + 0] = e0; o1[(i - 2) * 4 + 1] = e1; o1[(i - 2) * 4 + 2] = e2; o1[(i - 2) * 4 + 3] = e3; }
      }
      __bf16* dst = &mt[(k0 + 8 * r) * 136 + C0];
      *(bf16x8*)dst = o0;
      *(bf16x8*)(dst + 8) = o1;
    }
    WAVE_LDS_SYNC();
    bf16x8 af[4];
#pragma unroll
    for (int t = 0; t < 4; ++t)
      af[t] = *(const bf16x8*)&mt[c15 * 136 + t * 32 + q * 8];
    f32x4 acc[8] = {};
#pragma unroll
    for (int nt = 0; nt < 8; ++nt)
#pragma unroll
      for (int t = 0; t < 4; ++t)
        acc[nt] = __builtin_amdgcn_mfma_f32_16x16x32_bf16(af[t], bfr[nt][t], acc[nt], 0, 0, 0);
#pragma unroll
    for (int nt = 0; nt < 8; ++nt) {
      float m4 = fmaxf(fmaxf(acc[nt][0], acc[nt][1]), fmaxf(acc[nt][2], acc[nt][3]));
      m4 = fmaxf(m4, __shfl_xor(m4, 16));
      m4 = fmaxf(m4, __shfl_xor(m4, 32));
      if ((nt >> 1) == q) {
        float bias = (nt & 1) ? bbi1 : bbi0;
        h1e[nodec * 160 + nt * 16 + c15] = (__bf16)fmaxf(m4 + bias, 0.f);
      }
    }
    if (lane < 32) {  // append pos (bf16) + zero pad: cols 128..159
      __bf16 v = (__bf16)0.f;
      if (lane == 0) v = (__bf16)xp;
      else if (lane == 1) v = (__bf16)yp;
      else if (lane == 2) v = (__bf16)zp;
      h1e[nodec * 160 + 128 + lane] = v;
    }
  }
}

// ---------------------------------------------------------------- K3: u2' = [h1|pos|0] @ W2a + b2a (bf16 out)
__global__ __launch_bounds__(256) void mid_gemm_kernel(
    const __bf16* __restrict__ h1e, const float* __restrict__ W2a,
    const float* __restrict__ b2a, __bf16* __restrict__ u2p) {
  __shared__ LDSA __bf16 Wt[128 * 168];  // W2a^T [n][k], k padded 131->168
  const int tid = threadIdx.x;
  uint4 z = make_uint4(0, 0, 0, 0);
  for (int idx = tid; idx < 2688; idx += 256) ((uint4*)Wt)[idx] = z;
  __syncthreads();
  for (int idx = tid; idx < 131 * 32; idx += 256) {
    int k = idx >> 5, c4 = (idx & 31) * 4;
    float4 w = *(const float4*)&W2a[k * 128 + c4];
    Wt[(c4 + 0) * 168 + k] = (__bf16)w.x;
    Wt[(c4 + 1) * 168 + k] = (__bf16)w.y;
    Wt[(c4 + 2) * 168 + k] = (__bf16)w.z;
    Wt[(c4 + 3) * 168 + k] = (__bf16)w.w;
  }
  const int wave = tid >> 6, lane = tid & 63;
  const int q = lane >> 4, c15 = lane & 15;
  float biasr[8];
#pragma unroll
  for (int nt = 0; nt < 8; ++nt) biasr[nt] = b2a[nt * 16 + c15];
  __syncthreads();
  for (int tile = 0; tile < 4; ++tile) {  // 4 row-tiles/block: staging amortized
    const int row0 = blockIdx.x * 256 + tile * 64 + wave * 16;
    bf16x8 af[5];
#pragma unroll
    for (int t = 0; t < 5; ++t)
      af[t] = *(const bf16x8*)(h1e + (size_t)(row0 + c15) * 160 + t * 32 + q * 8);
    f32x4 acc[8] = {};
#pragma unroll
    for (int nt = 0; nt < 8; ++nt)
#pragma unroll
      for (int t = 0; t < 5; ++t) {
        bf16x8 bf = *(const bf16x8*)&Wt[(nt * 16 + c15) * 168 + t * 32 + q * 8];
        acc[nt] = __builtin_amdgcn_mfma_f32_16x16x32_bf16(af[t], bf, acc[nt], 0, 0, 0);
      }
#pragma unroll
    for (int nt = 0; nt < 8; ++nt) {
#pragma unroll
      for (int r = 0; r < 4; ++r)
        u2p[(size_t)(row0 + q * 4 + r) * 128 + nt * 16 + c15] = (__bf16)(acc[nt][r] + biasr[nt]);
    }
  }
}

// ---------------------------------------------------------------- K4: layer 2 + fused max pool
__global__ __launch_bounds__(256, 2) void layer2_kernel(
    const float* __restrict__ pos, const int* __restrict__ nbr,
    const __bf16* __restrict__ u2p, const float* __restrict__ W2a,
    const float* __restrict__ W2b, const float* __restrict__ b2b,
    int* __restrict__ gG) {
  __shared__ LDSA char smem[34816];  // Wbt aliased with { mt ; proj }
  __shared__ int gpart[128];
  __bf16* Wbt = (__bf16*)smem;
  const int tid = threadIdx.x;
  for (int idx = tid; idx < 16384; idx += 256) {
    int k = idx >> 7, n = idx & 127;
    int byteoff = n * 272 + ((k * 2) ^ (((n >> 3) & 7) << 4));
    *(__bf16*)((char*)Wbt + byteoff) = (__bf16)W2b[idx];
  }
  if (tid < 128) gpart[tid] = 0;
  __syncthreads();
  const int wave = tid >> 6, lane = tid & 63;
  const int q = lane >> 4, c15 = lane & 15;
  bf16x8 bfr[8][4];
#pragma unroll
  for (int nt = 0; nt < 8; ++nt)
#pragma unroll
    for (int t = 0; t < 4; ++t) {
      int row = nt * 16 + c15;
      int rbyte = row * 272 + (((t * 32 + q * 8) * 2) ^ (((row >> 3) & 7) << 4));
      bfr[nt][t] = *(const bf16x8*)((const char*)Wbt + rbyte);
    }
  __syncthreads();  // Wbt dead
  __bf16* mt = (__bf16*)smem + wave * 2176;
  float* proj = (float*)(smem + 17408) + wave * 128;
  const int cb = lane & 7, k0 = lane >> 3, C0 = cb * 16;
  const int c2 = lane * 2;
  const float r0a = W2a[16384 + c2], r0b = W2a[16384 + c2 + 1];
  const float r1a = W2a[16512 + c2], r1b = W2a[16512 + c2 + 1];
  const float r2a = W2a[16640 + c2], r2b = W2a[16640 + c2 + 1];
  const float bbi0 = b2b[q * 32 + c15], bbi1 = b2b[q * 32 + 16 + c15];
  // XCD swizzle: graph g's 32 blocks -> one XCD (blk%8 assumed XCD round-robin; perf-only)
  const int lb = blockIdx.x;
  const int xcd = lb & 7, slot = lb >> 3;
  const int b = xcd + 8 * (slot >> 5);
  const int bi = slot & 31;
  const size_t bbase = (size_t)b * 2048;
  const int p0 = bi * 64 + wave * 16;
  size_t node = bbase + p0;
  int j0 = nbr[node * 16 + k0];
  int j1 = nbr[node * 16 + k0 + 8];
  float px = pos[node * 3], py = pos[node * 3 + 1], pz = pos[node * 3 + 2];
  for (int it = 0; it < 16; ++it) {
    const int j0c = j0, j1c = j1;
    const float xp = px, yp = py, zp = pz;
    const size_t nodec = node;
    if (it < 15) {
      node = nodec + 1;
      j0 = nbr[node * 16 + k0];
      j1 = nbr[node * 16 + k0 + 8];
      px = pos[node * 3]; py = pos[node * 3 + 1]; pz = pos[node * 3 + 2];
    }
    const __bf16* ur0 = u2p + (size_t)(bbase + j0c) * 128 + C0;
    const __bf16* ur1 = u2p + (size_t)(bbase + j1c) * 128 + C0;
    bf16x8 ua0 = *(const bf16x8*)ur0, ua1 = *(const bf16x8*)(ur0 + 8);
    bf16x8 ub0 = *(const bf16x8*)ur1, ub1 = *(const bf16x8*)(ur1 + 8);
    float v0 = fmaf(xp, r0a, fmaf(yp, r1a, zp * r2a));
    float v1 = fmaf(xp, r0b, fmaf(yp, r1b, zp * r2b));
    *(float2*)&proj[c2] = make_float2(v0, v1);
    WAVE_LDS_SYNC();
    float pj[16];
#pragma unroll
    for (int i = 0; i < 4; ++i) *(float4*)&pj[4 * i] = *(const float4*)&proj[C0 + 4 * i];
#pragma unroll
    for (int r = 0; r < 2; ++r) {
      bf16x8 u0 = r ? ub0 : ua0, u1 = r ? ub1 : ua1;
      bf16x8 o0, o1;
#pragma unroll
      for (int e = 0; e < 8; ++e) o0[e] = (__bf16)fmaxf((float)u0[e] - pj[e], 0.f);
#pragma unroll
      for (int e = 0; e < 8; ++e) o1[e] = (__bf16)fmaxf((float)u1[e] - pj[8 + e], 0.f);
      __bf16* dst = &mt[(k0 + 8 * r) * 136 + C0];
      *(bf16x8*)dst = o0;
      *(bf16x8*)(dst + 8) = o1;
    }
    WAVE_LDS_SYNC();
    bf16x8 af[4];
#pragma unroll
    for (int t = 0; t < 4; ++t)
      af[t] = *(const bf16x8*)&mt[c15 * 136 + t * 32 + q * 8];
    f32x4 acc[8] = {};
#pragma unroll
    for (int nt = 0; nt < 8; ++nt)
#pragma unroll
      for (int t = 0; t < 4; ++t)
        acc[nt] = __builtin_amdgcn_mfma_f32_16x16x32_bf16(af[t], bfr[nt][t], acc[nt], 0, 0, 0);
#pragma unroll
    for (int nt = 0; nt < 8; ++nt) {
      float m4 = fmaxf(fmaxf(acc[nt][0], acc[nt][1]), fmaxf(acc[nt][2], acc[nt][3]));
      m4 = fmaxf(m4, __shfl_xor(m4, 16));
      m4 = fmaxf(m4, __shfl_xor(m4, 32));
      if ((nt >> 1) == q) {
        float bias = (nt & 1) ? bbi1 : bbi0;
        float h = fmaxf(m4 + bias, 0.f);
        atomicMax(&gpart[nt * 16 + c15], __float_as_int(h));  // h>=0: int-max == float-max
      }
    }
  }
  __syncthreads();
  if (tid < 128) atomicMax(&gG[b * 128 + tid], gpart[tid]);
}

// ---------------------------------------------------------------- K5: classifier
__global__ __launch_bounds__(64) void cls_kernel(const int* __restrict__ gG,
                                                 const float* __restrict__ Wc,
                                                 const float* __restrict__ bc,
                                                 float* __restrict__ out) {
  const int b = blockIdx.x, lane = threadIdx.x;
  float g1 = __int_as_float(gG[b * 128 + lane]);
  float g2 = __int_as_float(gG[b * 128 + 64 + lane]);
  float accn[10];
#pragma unroll
  for (int n = 0; n < 10; ++n)
    accn[n] = g1 * Wc[lane * 10 + n] + g2 * Wc[(64 + lane) * 10 + n];
#pragma unroll
  for (int n = 0; n < 10; ++n) {
#pragma unroll
    for (int off = 32; off >= 1; off >>= 1) accn[n] += __shfl_xor(accn[n], off);
  }
  if (lane == 0) {
#pragma unroll
    for (int n = 0; n < 10; ++n) out[b * 10 + n] = accn[n] + bc[n];
  }
}

// ---------------------------------------------------------------- launcher
extern "C" void kernel_launch(void* const* d_in, const int* in_sizes, int n_in,
                              void* d_out, int out_size, void* d_ws, size_t ws_size,
                              hipStream_t stream) {
  const float* pos = (const float*)d_in[0];
  // d_in[1] = batch (unused: graphs are equal-size, sorted)
  const float* W1a = (const float*)d_in[2];
  const float* b1a = (const float*)d_in[3];
  const float* W1b = (const float*)d_in[4];
  const float* b1b = (const float*)d_in[5];
  const float* W2a = (const float*)d_in[6];
  const float* b2a = (const float*)d_in[7];
  const float* W2b = (const float*)d_in[8];
  const float* b2b = (const float*)d_in[9];
  const float* Wc  = (const float*)d_in[10];
  const float* bc  = (const float*)d_in[11];

  char* ws = (char*)d_ws;
  int*    nbr = (int*)ws;                          //  4 MB : [65536][16]
  __bf16* h1e = (__bf16*)(ws + 4194304);           // 20 MB : [65536][160]
  __bf16* u2p = (__bf16*)(ws + 25165824);          // 16 MB : [65536][128] bf16
  int*    gG  = (int*)(ws + 41943040);             // 16 KB : [32][128]
  float*  out = (float*)d_out;

  hipMemsetAsync(gG, 0, 32 * 128 * sizeof(int), stream);  // relu>=0, bits(0)==0.0f
  knn_kernel<<<1024, 512, 0, stream>>>(pos, nbr);
  layer1_kernel<<<1024, 256, 0, stream>>>(pos, nbr, W1a, b1a, W1b, b1b, h1e);
  mid_gemm_kernel<<<256, 256, 0, stream>>>(h1e, W2a, b2a, u2p);
  layer2_kernel<<<1024, 256, 0, stream>>>(pos, nbr, u2p, W2a, W2b, b2b, gG);
  cls_kernel<<<32, 64, 0, stream>>>(gG, Wc, bc, out);
}

// Round 11
// 328.045 us; speedup vs baseline: 1.0473x; 1.0077x over previous
//
#include <hip/hip_runtime.h>

// PointNet on MI355X. B=32, P=2048, K=16, NHID=128, NCLS=10.
//   K1 knn      : brute-force d2; per-lane streaming top-3 VALUES (med3 chain + value-only m4),
//                 indices s1/s2 tracked in-loop; s3 recovered by conditional bit-match rescan
//                 (trigger __any(k3<=V), ~15-20%): identical d2 formula + bit-preserving med3 =>
//                 bits(d2)==bits(m3) identifies the 3rd-smallest exactly. SET-based selection:
//                 32-step ballot binary search for V = 16th-smallest buffered key, ballot-ranked
//                 scatter of {key<V} + (16-cnt) of {key==V}. Exact fallback on __any(k4<V)
//                 (~0.4%): 16-round u64 pop-with-refill; lanes with k3>V carry s3=0 harmlessly.
//   K2 layer1   : msg = relu(pos_j*(A+B) + (b1a - pos_p*B)); v = msg @ W1b (MFMA); h1 = relu(max_k v + b1b)
//                 Wave-private LDS (no block barriers in loop); nbr/pos prefetched one iter ahead.
//   K3 midgemm  : u2' = [h1|pos|0] @ W2a(all 131 rows) + b2a -> bf16. 4 row-tiles/block.
//   K4 layer2   : msg = relu(u2'[j] - pos_p*R); v = msg @ W2b (MFMA); fused global max pool.
//                 u2p gather bf16 + XCD swizzle for L2 residency.
//   K5 cls      : out = g @ Wc + bc
// MFMA layouts per verified m89/m97 mappings.
// Session ledger: layers are latency-structure-bound (restructures r6/r9 negative; polish r7/r8
// null/negative) — kept in their r3 (empirical-optimum) form. This round isolates the knn
// s3-rescan lever (carried in 4 passing benches but never A/B'd clean).

typedef __bf16 bf16x8 __attribute__((ext_vector_type(8)));
typedef float  f32x4  __attribute__((ext_vector_type(4)));

#define LDSA __attribute__((aligned(16)))
#define WAVE_LDS_SYNC() __asm__ volatile("s_waitcnt lgkmcnt(0)" ::: "memory")

// ---------------------------------------------------------------- K1: KNN
__global__ __launch_bounds__(512, 4) void knn_kernel(const float* __restrict__ pos,
                                                     int* __restrict__ nbr) {
  __shared__ LDSA float4 P4[2048];  // {x,y,z,|p|^2}
  const int blk = blockIdx.x;
  const int b = blk >> 5;
  const int tid = threadIdx.x;
  const size_t bbase = (size_t)b * 2048;
  for (int idx = tid; idx < 2048; idx += 512) {
    const float* pp = pos + (bbase + idx) * 3;
    float x = pp[0], y = pp[1], z = pp[2];
    P4[idx] = make_float4(x, y, z, fmaf(z, z, fmaf(y, y, x * x)));
  }
  __syncthreads();
  const int wave = tid >> 6, lane = tid & 63;
  const int p0 = (blk & 31) * 64 + wave * 8;   // 8 points per wave
  const unsigned long long below = (1ull << lane) - 1ull;
  const float FINF = __uint_as_float(0x7F800000u);
  for (int it = 0; it < 8; ++it) {
    const int pl = p0 + it;
    const float4 P = P4[pl];
    // ---- phase 1: streaming per-lane sorted top-3 values (+m4); indices s1,s2 only ----
    float m1 = FINF, m2 = FINF, m3 = FINF, m4 = FINF;
    unsigned s1 = 0, s2 = 0;
#pragma unroll 8
    for (int i = 0; i < 32; ++i) {
      int c = lane + (i << 6);
      float4 Q = P4[c];
      float d2 = (P.w + Q.w) - 2.0f * fmaf(P.z, Q.z, fmaf(P.y, Q.y, P.x * Q.x));
      bool c1 = d2 < m1, c2 = d2 < m2;
      float nm4 = __builtin_amdgcn_fmed3f(m3, m4, d2);
      float nm3 = __builtin_amdgcn_fmed3f(m2, m3, d2);
      float nm2 = __builtin_amdgcn_fmed3f(m1, m2, d2);
      float nm1 = fminf(m1, d2);
      s2 = c1 ? s1 : (c2 ? (unsigned)c : s2);
      s1 = c1 ? (unsigned)c : s1;
      m1 = nm1; m2 = nm2; m3 = nm3; m4 = nm4;
    }
    // ---- monotone float->u32 keys ----
    unsigned k1 = __float_as_uint(m1); k1 = ((int)k1 < 0) ? ~k1 : (k1 | 0x80000000u);
    unsigned k2 = __float_as_uint(m2); k2 = ((int)k2 < 0) ? ~k2 : (k2 | 0x80000000u);
    unsigned k3 = __float_as_uint(m3); k3 = ((int)k3 < 0) ? ~k3 : (k3 | 0x80000000u);
    unsigned k4 = __float_as_uint(m4); k4 = ((int)k4 < 0) ? ~k4 : (k4 | 0x80000000u);
    // ---- phase 2: binary search for V = 16th smallest buffered key ----
    unsigned v = 0;
#pragma unroll
    for (int bit = 31; bit >= 0; --bit) {
      unsigned t = v | (1u << bit);
      int cnt = __popcll(__ballot(k1 < t)) + __popcll(__ballot(k2 < t)) +
                __popcll(__ballot(k3 < t));
      if (cnt < 16) v = t;  // keep invariant count(< v) < 16; final v = 16th smallest
    }
    const unsigned V = v;
    // ---- s3 recovery rescan: only when some lane's 3rd key can be emitted ----
    unsigned s3 = 0;
    if (__any(k3 <= V)) {
      const unsigned m3b = __float_as_uint(m3);
#pragma unroll 8
      for (int i = 0; i < 32; ++i) {
        int c = lane + (i << 6);
        float4 Q = P4[c];
        float d2 = (P.w + Q.w) - 2.0f * fmaf(P.z, Q.z, fmaf(P.y, Q.y, P.x * Q.x));
        if (__float_as_uint(d2) == m3b) s3 = (unsigned)c;
      }
    }
    const long long outbase = ((long long)bbase + pl) * 16;
    if (__any(k4 < V)) {
      // ---- exact fallback (~0.4%): a lane's UNBUFFERED 4th is < V. 16-round u64
      //      pop-with-refill. Lanes with k3>V have s3=0: their K3 key exceeds V and at
      //      least 16 smaller keys exist, so (k3,0) is never popped. ----
      unsigned long long K1 = ((unsigned long long)k1 << 32) | s1;
      unsigned long long K2 = ((unsigned long long)k2 << 32) | s2;
      unsigned long long K3 = ((unsigned long long)k3 << 32) | s3;
      unsigned long long lastk = 0;
      for (int r = 0; r < 16; ++r) {
        unsigned long long k = K1, kmin = K1;
#pragma unroll
        for (int off = 1; off < 64; off <<= 1) {
          unsigned long long o = __shfl_xor(kmin, off);
          kmin = (o < kmin) ? o : kmin;
        }
        if (lane == r) nbr[outbase + r] = (int)(kmin & 0xFFFFFFFFull);
        if (k == kmin) { lastk = k; K1 = K2; K2 = K3; K3 = ~0ull; }
        if (r < 15 && __any(K1 == ~0ull)) {
          if (K1 == ~0ull) {
            unsigned long long best = ~0ull;
            for (int i = 0; i < 32; ++i) {
              int c = lane + (i << 6);
              float4 Q = P4[c];
              float d2 = (P.w + Q.w) - 2.0f * fmaf(P.z, Q.z, fmaf(P.y, Q.y, P.x * Q.x));
              unsigned u = __float_as_uint(d2);
              u = ((int)u < 0) ? ~u : (u | 0x80000000u);
              unsigned long long kc = ((unsigned long long)u << 32) | (unsigned)c;
              bool ok = (kc > lastk) & (kc < best);
              best = ok ? kc : best;
            }
            K1 = best;
          }
        }
      }
    } else {
      // ---- set emission: all keys < V, plus (16 - count) of the == V ties ----
      unsigned long long L1 = __ballot(k1 < V), L2 = __ballot(k2 < V), L3 = __ballot(k3 < V);
      unsigned long long E1 = __ballot(k1 == V), E2 = __ballot(k2 == V), E3 = __ballot(k3 == V);
      int cA = __popcll(L1), cB = cA + __popcll(L2), cT = cB + __popcll(L3);
      int eA = __popcll(E1), eB = eA + __popcll(E2);
      {
        bool lt = k1 < V, eq = k1 == V;
        int plt = __popcll(L1 & below);
        int peq = cT + __popcll(E1 & below);
        int p = lt ? plt : peq;
        if (lt || (eq && peq < 16)) nbr[outbase + p] = (int)s1;
      }
      {
        bool lt = k2 < V, eq = k2 == V;
        int plt = cA + __popcll(L2 & below);
        int peq = cT + eA + __popcll(E2 & below);
        int p = lt ? plt : peq;
        if (lt || (eq && peq < 16)) nbr[outbase + p] = (int)s2;
      }
      {
        bool lt = k3 < V, eq = k3 == V;
        int plt = cB + __popcll(L3 & below);
        int peq = cT + eB + __popcll(E3 & below);
        int p = lt ? plt : peq;
        if (lt || (eq && peq < 16)) nbr[outbase + p] = (int)s3;
      }
    }
  }
}

// ---------------------------------------------------------------- K2: layer 1
__global__ __launch_bounds__(256, 2) void layer1_kernel(
    const float* __restrict__ pos, const int* __restrict__ nbr,
    const float* __restrict__ W1a, const float* __restrict__ b1a,
    const float* __restrict__ W1b, const float* __restrict__ b1b,
    __bf16* __restrict__ h1e) {
  __shared__ LDSA char smem[34816];  // Wbt aliased with { mt ; base }
  __bf16* Wbt = (__bf16*)smem;
  const int tid = threadIdx.x;
  // XOR-swizzled staging: row n stride 272 B (68 dw == 4 mod 32; x8 wraps -> same-(n>>3)
  // lanes 8-way conflict). byte ^= ((n>>3)&7)<<4 permutes 16B blocks, spreading banks.
  for (int idx = tid; idx < 16384; idx += 256) {
    int k = idx >> 7, n = idx & 127;
    int byteoff = n * 272 + ((k * 2) ^ (((n >> 3) & 7) << 4));
    *(__bf16*)((char*)Wbt + byteoff) = (__bf16)W1b[idx];
  }
  __syncthreads();
  const int wave = tid >> 6, lane = tid & 63;
  const int q = lane >> 4, c15 = lane & 15;
  bf16x8 bfr[8][4];  // W1b^T fragments resident (128 VGPRs)
#pragma unroll
  for (int nt = 0; nt < 8; ++nt)
#pragma unroll
    for (int t = 0; t < 4; ++t) {
      int row = nt * 16 + c15;
      int rbyte = row * 272 + (((t * 32 + q * 8) * 2) ^ (((row >> 3) & 7) << 4));
      bfr[nt][t] = *(const bf16x8*)((const char*)Wbt + rbyte);
    }
  __syncthreads();  // Wbt dead: space reused for mt/base
  __bf16* mt = (__bf16*)smem + wave * 2176;          // [16 rows][136]
  float* base = (float*)(smem + 17408) + wave * 128;
  const int cb = lane & 7, k0 = lane >> 3, C0 = cb * 16;
  float4 s0h[4], s1h[4], s2h[4];  // (A+B) rows for this lane's 16 channels
#pragma unroll
  for (int i = 0; i < 4; ++i) {
    float4 a0 = *(const float4*)&W1a[      C0 + 4 * i], r0 = *(const float4*)&W1a[384 + C0 + 4 * i];
    float4 a1 = *(const float4*)&W1a[128 + C0 + 4 * i], r1 = *(const float4*)&W1a[512 + C0 + 4 * i];
    float4 a2 = *(const float4*)&W1a[256 + C0 + 4 * i], r2 = *(const float4*)&W1a[640 + C0 + 4 * i];
    s0h[i] = make_float4(a0.x + r0.x, a0.y + r0.y, a0.z + r0.z, a0.w + r0.w);
    s1h[i] = make_float4(a1.x + r1.x, a1.y + r1.y, a1.z + r1.z, a1.w + r1.w);
    s2h[i] = make_float4(a2.x + r2.x, a2.y + r2.y, a2.z + r2.z, a2.w + r2.w);
  }
  const int c2 = lane * 2;
  const float br0a = W1a[384 + c2], br0b = W1a[384 + c2 + 1];
  const float br1a = W1a[512 + c2], br1b = W1a[512 + c2 + 1];
  const float br2a = W1a[640 + c2], br2b = W1a[640 + c2 + 1];
  const float ba0 = b1a[c2], ba1 = b1a[c2 + 1];
  const float bbi0 = b1b[q * 32 + c15], bbi1 = b1b[q * 32 + 16 + c15];
  const int blk = blockIdx.x, b = blk >> 5;
  const size_t bbase = (size_t)b * 2048;
  const int p0 = (blk & 31) * 64 + wave * 16;
  size_t node = bbase + p0;
  // prefetch it=0
  int j0 = nbr[node * 16 + k0];
  int j1 = nbr[node * 16 + k0 + 8];
  float px = pos[node * 3], py = pos[node * 3 + 1], pz = pos[node * 3 + 2];
  for (int it = 0; it < 16; ++it) {
    const int j0c = j0, j1c = j1;
    const float xp = px, yp = py, zp = pz;
    const size_t nodec = node;
    if (it < 15) {  // prefetch next iteration's indices + own pos
      node = nodec + 1;
      j0 = nbr[node * 16 + k0];
      j1 = nbr[node * 16 + k0 + 8];
      px = pos[node * 3]; py = pos[node * 3 + 1]; pz = pos[node * 3 + 2];
    }
    const float* pj0 = pos + (bbase + j0c) * 3;
    const float* pj1 = pos + (bbase + j1c) * 3;
    const float xa = pj0[0], ya = pj0[1], za = pj0[2];
    const float xb = pj1[0], yb = pj1[1], zb = pj1[2];
    float v0 = ba0 - fmaf(xp, br0a, fmaf(yp, br1a, zp * br2a));
    float v1 = ba1 - fmaf(xp, br0b, fmaf(yp, br1b, zp * br2b));
    *(float2*)&base[c2] = make_float2(v0, v1);
    WAVE_LDS_SYNC();
    float4 bb[4];
#pragma unroll
    for (int i = 0; i < 4; ++i) bb[i] = *(const float4*)&base[C0 + 4 * i];
#pragma unroll
    for (int r = 0; r < 2; ++r) {
      const float xj = r ? xb : xa, yj = r ? yb : ya, zj = r ? zb : za;
      bf16x8 o0, o1;
#pragma unroll
      for (int i = 0; i < 4; ++i) {
        float mx = fmaf(xj, s0h[i].x, fmaf(yj, s1h[i].x, fmaf(zj, s2h[i].x, bb[i].x)));
        float my = fmaf(xj, s0h[i].y, fmaf(yj, s1h[i].y, fmaf(zj, s2h[i].y, bb[i].y)));
        float mz = fmaf(xj, s0h[i].z, fmaf(yj, s1h[i].z, fmaf(zj, s2h[i].z, bb[i].z)));
        float mw = fmaf(xj, s0h[i].w, fmaf(yj, s1h[i].w, fmaf(zj, s2h[i].w, bb[i].w)));
        __bf16 e0 = (__bf16)fmaxf(mx, 0.f), e1 = (__bf16)fmaxf(my, 0.f);
        __bf16 e2 = (__bf16)fmaxf(mz, 0.f), e3 = (__bf16)fmaxf(mw, 0.f);
        if (i < 2) { o0[i * 4 + 0] = e0; o0[i * 4 + 1] = e1; o0[i * 4 + 2] = e2; o0[i * 4 + 3] = e3; }
        else { o1[(i - 2) * 4 + 0] = e0; o1[(i - 2) * 4 + 1] = e1; o1[(i - 2) * 4 + 2] = e2; o1[(i - 2) * 4 + 3] = e3; }
      }
      __bf16* dst = &mt[(k0 + 8 * r) * 136 + C0];
      *(bf16x8*)dst = o0;
      *(bf16x8*)(dst + 8) = o1;
    }
    WAVE_LDS_SYNC();
    bf16x8 af[4];
#pragma unroll
    for (int t = 0; t < 4; ++t)
      af[t] = *(const bf16x8*)&mt[c15 * 136 + t * 32 + q * 8];
    f32x4 acc[8] = {};
#pragma unroll
    for (int nt = 0; nt < 8; ++nt)
#pragma unroll
      for (int t = 0; t < 4; ++t)
        acc[nt] = __builtin_amdgcn_mfma_f32_16x16x32_bf16(af[t], bfr[nt][t], acc[nt], 0, 0, 0);
#pragma unroll
    for (int nt = 0; nt < 8; ++nt) {
      float m4 = fmaxf(fmaxf(acc[nt][0], acc[nt][1]), fmaxf(acc[nt][2], acc[nt][3]));
      m4 = fmaxf(m4, __shfl_xor(m4, 16));
      m4 = fmaxf(m4, __shfl_xor(m4, 32));
      if ((nt >> 1) == q) {
        float bias = (nt & 1) ? bbi1 : bbi0;
        h1e[nodec * 160 + nt * 16 + c15] = (__bf16)fmaxf(m4 + bias, 0.f);
      }
    }
    if (lane < 32) {  // append pos (bf16) + zero pad: cols 128..159
      __bf16 v = (__bf16)0.f;
      if (lane == 0) v = (__bf16)xp;
      else if (lane == 1) v = (__bf16)yp;
      else if (lane == 2) v = (__bf16)zp;
      h1e[nodec * 160 + 128 + lane] = v;
    }
  }
}

// ---------------------------------------------------------------- K3: u2' = [h1|pos|0] @ W2a + b2a (bf16 out)
__global__ __launch_bounds__(256) void mid_gemm_kernel(
    const __bf16* __restrict__ h1e, const float* __restrict__ W2a,
    const float* __restrict__ b2a, __bf16* __restrict__ u2p) {
  __shared__ LDSA __bf16 Wt[128 * 168];  // W2a^T [n][k], k padded 131->168
  const int tid = threadIdx.x;
  uint4 z = make_uint4(0, 0, 0, 0);
  for (int idx = tid; idx < 2688; idx += 256) ((uint4*)Wt)[idx] = z;
  __syncthreads();
  for (int idx = tid; idx < 131 * 32; idx += 256) {
    int k = idx >> 5, c4 = (idx & 31) * 4;
    float4 w = *(const float4*)&W2a[k * 128 + c4];
    Wt[(c4 + 0) * 168 + k] = (__bf16)w.x;
    Wt[(c4 + 1) * 168 + k] = (__bf16)w.y;
    Wt[(c4 + 2) * 168 + k] = (__bf16)w.z;
    Wt[(c4 + 3) * 168 + k] = (__bf16)w.w;
  }
  const int wave = tid >> 6, lane = tid & 63;
  const int q = lane >> 4, c15 = lane & 15;
  float biasr[8];
#pragma unroll
  for (int nt = 0; nt < 8; ++nt) biasr[nt] = b2a[nt * 16 + c15];
  __syncthreads();
  for (int tile = 0; tile < 4; ++tile) {  // 4 row-tiles/block: staging amortized
    const int row0 = blockIdx.x * 256 + tile * 64 + wave * 16;
    bf16x8 af[5];
#pragma unroll
    for (int t = 0; t < 5; ++t)
      af[t] = *(const bf16x8*)(h1e + (size_t)(row0 + c15) * 160 + t * 32 + q * 8);
    f32x4 acc[8] = {};
#pragma unroll
    for (int nt = 0; nt < 8; ++nt)
#pragma unroll
      for (int t = 0; t < 5; ++t) {
        bf16x8 bf = *(const bf16x8*)&Wt[(nt * 16 + c15) * 168 + t * 32 + q * 8];
        acc[nt] = __builtin_amdgcn_mfma_f32_16x16x32_bf16(af[t], bf, acc[nt], 0, 0, 0);
      }
#pragma unroll
    for (int nt = 0; nt < 8; ++nt) {
#pragma unroll
      for (int r = 0; r < 4; ++r)
        u2p[(size_t)(row0 + q * 4 + r) * 128 + nt * 16 + c15] = (__bf16)(acc[nt][r] + biasr[nt]);
    }
  }
}

// ---------------------------------------------------------------- K4: layer 2 + fused max pool
__global__ __launch_bounds__(256, 2) void layer2_kernel(
    const float* __restrict__ pos, const int* __restrict__ nbr,
    const __bf16* __restrict__ u2p, const float* __restrict__ W2a,
    const float* __restrict__ W2b, const float* __restrict__ b2b,
    int* __restrict__ gG) {
  __shared__ LDSA char smem[34816];  // Wbt aliased with { mt ; proj }
  __shared__ int gpart[128];
  __bf16* Wbt = (__bf16*)smem;
  const int tid = threadIdx.x;
  for (int idx = tid; idx < 16384; idx += 256) {
    int k = idx >> 7, n = idx & 127;
    int byteoff = n * 272 + ((k * 2) ^ (((n >> 3) & 7) << 4));
    *(__bf16*)((char*)Wbt + byteoff) = (__bf16)W2b[idx];
  }
  if (tid < 128) gpart[tid] = 0;
  __syncthreads();
  const int wave = tid >> 6, lane = tid & 63;
  const int q = lane >> 4, c15 = lane & 15;
  bf16x8 bfr[8][4];
#pragma unroll
  for (int nt = 0; nt < 8; ++nt)
#pragma unroll
    for (int t = 0; t < 4; ++t) {
      int row = nt * 16 + c15;
      int rbyte = row * 272 + (((t * 32 + q * 8) * 2) ^ (((row >> 3) & 7) << 4));
      bfr[nt][t] = *(const bf16x8*)((const char*)Wbt + rbyte);
    }
  __syncthreads();  // Wbt dead
  __bf16* mt = (__bf16*)smem + wave * 2176;
  float* proj = (float*)(smem + 17408) + wave * 128;
  const int cb = lane & 7, k0 = lane >> 3, C0 = cb * 16;
  const int c2 = lane * 2;
  const float r0a = W2a[16384 + c2], r0b = W2a[16384 + c2 + 1];
  const float r1a = W2a[16512 + c2], r1b = W2a[16512 + c2 + 1];
  const float r2a = W2a[16640 + c2], r2b = W2a[16640 + c2 + 1];
  const float bbi0 = b2b[q * 32 + c15], bbi1 = b2b[q * 32 + 16 + c15];
  // XCD swizzle: graph g's 32 blocks -> one XCD (blk%8 assumed XCD round-robin; perf-only)
  const int lb = blockIdx.x;
  const int xcd = lb & 7, slot = lb >> 3;
  const int b = xcd + 8 * (slot >> 5);
  const int bi = slot & 31;
  const size_t bbase = (size_t)b * 2048;
  const int p0 = bi * 64 + wave * 16;
  size_t node = bbase + p0;
  int j0 = nbr[node * 16 + k0];
  int j1 = nbr[node * 16 + k0 + 8];
  float px = pos[node * 3], py = pos[node * 3 + 1], pz = pos[node * 3 + 2];
  for (int it = 0; it < 16; ++it) {
    const int j0c = j0, j1c = j1;
    const float xp = px, yp = py, zp = pz;
    const size_t nodec = node;
    if (it < 15) {
      node = nodec + 1;
      j0 = nbr[node * 16 + k0];
      j1 = nbr[node * 16 + k0 + 8];
      px = pos[node * 3]; py = pos[node * 3 + 1]; pz = pos[node * 3 + 2];
    }
    const __bf16* ur0 = u2p + (size_t)(bbase + j0c) * 128 + C0;
    const __bf16* ur1 = u2p + (size_t)(bbase + j1c) * 128 + C0;
    bf16x8 ua0 = *(const bf16x8*)ur0, ua1 = *(const bf16x8*)(ur0 + 8);
    bf16x8 ub0 = *(const bf16x8*)ur1, ub1 = *(const bf16x8*)(ur1 + 8);
    float v0 = fmaf(xp, r0a, fmaf(yp, r1a, zp * r2a));
    float v1 = fmaf(xp, r0b, fmaf(yp, r1b, zp * r2b));
    *(float2*)&proj[c2] = make_float2(v0, v1);
    WAVE_LDS_SYNC();
    float pj[16];
#pragma unroll
    for (int i = 0; i < 4; ++i) *(float4*)&pj[4 * i] = *(const float4*)&proj[C0 + 4 * i];
#pragma unroll
    for (int r = 0; r < 2; ++r) {
      bf16x8 u0 = r ? ub0 : ua0, u1 = r ? ub1 : ua1;
      bf16x8 o0, o1;
#pragma unroll
      for (int e = 0; e < 8; ++e) o0[e] = (__bf16)fmaxf((float)u0[e] - pj[e], 0.f);
#pragma unroll
      for (int e = 0; e < 8; ++e) o1[e] = (__bf16)fmaxf((float)u1[e] - pj[8 + e], 0.f);
      __bf16* dst = &mt[(k0 + 8 * r) * 136 + C0];
      *(bf16x8*)dst = o0;
      *(bf16x8*)(dst + 8) = o1;
    }
    WAVE_LDS_SYNC();
    bf16x8 af[4];
#pragma unroll
    for (int t = 0; t < 4; ++t)
      af[t] = *(const bf16x8*)&mt[c15 * 136 + t * 32 + q * 8];
    f32x4 acc[8] = {};
#pragma unroll
    for (int nt = 0; nt < 8; ++nt)
#pragma unroll
      for (int t = 0; t < 4; ++t)
        acc[nt] = __builtin_amdgcn_mfma_f32_16x16x32_bf16(af[t], bfr[nt][t], acc[nt], 0, 0, 0);
#pragma unroll
    for (int nt = 0; nt < 8; ++nt) {
      float m4 = fmaxf(fmaxf(acc[nt][0], acc[nt][1]), fmaxf(acc[nt][2], acc[nt][3]));
      m4 = fmaxf(m4, __shfl_xor(m4, 16));
      m4 = fmaxf(m4, __shfl_xor(m4, 32));
      if ((nt >> 1) == q) {
        float bias = (nt & 1) ? bbi1 : bbi0;
        float h = fmaxf(m4 + bias, 0.f);
        atomicMax(&gpart[nt * 16 + c15], __float_as_int(h));  // h>=0: int-max == float-max
      }
    }
  }
  __syncthreads();
  if (tid < 128) atomicMax(&gG[b * 128 + tid], gpart[tid]);
}

// ---------------------------------------------------------------- K5: classifier
__global__ __launch_bounds__(64) void cls_kernel(const int* __restrict__ gG,
                                                 const float* __restrict__ Wc,
                                                 const float* __restrict__ bc,
                                                 float* __restrict__ out) {
  const int b = blockIdx.x, lane = threadIdx.x;
  float g1 = __int_as_float(gG[b * 128 + lane]);
  float g2 = __int_as_float(gG[b * 128 + 64 + lane]);
  float accn[10];
#pragma unroll
  for (int n = 0; n < 10; ++n)
    accn[n] = g1 * Wc[lane * 10 + n] + g2 * Wc[(64 + lane) * 10 + n];
#pragma unroll
  for (int n = 0; n < 10; ++n) {
#pragma unroll
    for (int off = 32; off >= 1; off >>= 1) accn[n] += __shfl_xor(accn[n], off);
  }
  if (lane == 0) {
#pragma unroll
    for (int n = 0; n < 10; ++n) out[b * 10 + n] = accn[n] + bc[n];
  }
}

// ---------------------------------------------------------------- launcher
extern "C" void kernel_launch(void* const* d_in, const int* in_sizes, int n_in,
                              void* d_out, int out_size, void* d_ws, size_t ws_size,
                              hipStream_t stream) {
  const float* pos = (const float*)d_in[0];
  // d_in[1] = batch (unused: graphs are equal-size, sorted)
  const float* W1a = (const float*)d_in[2];
  const float* b1a = (const float*)d_in[3];
  const float* W1b = (const float*)d_in[4];
  const float* b1b = (const float*)d_in[5];
  const float* W2a = (const float*)d_in[6];
  const float* b2a = (const float*)d_in[7];
  const float* W2b = (const float*)d_in[8];
  const float* b2b = (const float*)d_in[9];
  const float* Wc  = (const float*)d_in[10];
  const float* bc  = (const float*)d_in[11];

  char* ws = (char*)d_ws;
  int*    nbr = (int*)ws;                          //  4 MB : [65536][16]
  __bf16* h1e = (__bf16*)(ws + 4194304);           // 20 MB : [65536][160]
  __bf16* u2p = (__bf16*)(ws + 25165824);          // 16 MB : [65536][128] bf16
  int*    gG  = (int*)(ws + 41943040);             // 16 KB : [32][128]
  float*  out = (float*)d_out;

  hipMemsetAsync(gG, 0, 32 * 128 * sizeof(int), stream);  // relu>=0, bits(0)==0.0f
  knn_kernel<<<1024, 512, 0, stream>>>(pos, nbr);
  layer1_kernel<<<1024, 256, 0, stream>>>(pos, nbr, W1a, b1a, W1b, b1b, h1e);
  mid_gemm_kernel<<<256, 256, 0, stream>>>(h1e, W2a, b2a, u2p);
  layer2_kernel<<<1024, 256, 0, stream>>>(pos, nbr, u2p, W2a, W2b, b2b, gG);
  cls_kernel<<<32, 64, 0, stream>>>(gG, Wc, bc, out);
}